// Round 8
// baseline (300.260 us; speedup 1.0000x reference)
//
#include <hip/hip_runtime.h>

#define N_IMG 8
#define CIN   128
#define H_IN  56
#define W_IN  56
#define COUT  128
#define HW    3136
#define TROWS 8                       // tile rows [ho-3, ho+4]
#define TILE_BYTES (TROWS * 56 * 256) // 114688
#define PMC_OFF  TILE_BYTES
#define PMW_OFF  (TILE_BYTES + 2304)
#define BLDS_OFF (TILE_BYTES + 2304 + 9216)
#define SMEM_TOTAL (BLDS_OFF + 32768) // 158976 <= 163840
#define SCRAP_OFF 8000000ULL

typedef __attribute__((ext_vector_type(8))) short short8;
typedef __attribute__((ext_vector_type(4))) float f32x4;
typedef __attribute__((ext_vector_type(4))) int i32x4v;

__device__ __forceinline__ unsigned short f2b(float f) {
    unsigned u = __builtin_bit_cast(unsigned, f);
    u = u + 0x7FFFu + ((u >> 16) & 1u);
    return (unsigned short)(u >> 16);
}
__device__ __forceinline__ float b2f(unsigned short h) {
    unsigned u = ((unsigned)h) << 16;
    return __builtin_bit_cast(float, u);
}
__device__ __forceinline__ void keep8(short8 v) {
    i32x4v i = __builtin_bit_cast(i32x4v, v);
    asm volatile("" :: "v"(i[0]), "v"(i[1]), "v"(i[2]), "v"(i[3]));
}
__device__ __forceinline__ void gload16(const void* g, void* l) {
    __builtin_amdgcn_global_load_lds(
        (const __attribute__((address_space(1))) unsigned int*)g,
        (__attribute__((address_space(3))) unsigned int*)l, 16, 0, 0);
}

// blocks 0..783: x (N,C,H,W) f32 -> xt (N,H,W,C) bf16 (linear NHWC)
// blocks 784..855: weight -> wr[tap][kg][f][lane][8] bf16 (B-fragment-linear)
__global__ __launch_bounds__(256) void prep_kernel(const float* __restrict__ x,
                                                   const float* __restrict__ w,
                                                   unsigned short* __restrict__ xt,
                                                   unsigned short* __restrict__ wr) {
    int b = blockIdx.x;
    int tid = threadIdx.x;
    if (b < 784) {
        int c = tid & 127;
        int half = tid >> 7;
        int n = b / 98;
        int hw0 = (b - n * 98) * 32 + half * 16;
        const float* xp = x + ((size_t)(n * CIN + c)) * HW + hw0;
        unsigned short* op = xt + ((size_t)n * HW + hw0) * CIN + c;
#pragma unroll
        for (int r = 0; r < 16; ++r) op[r * CIN] = f2b(xp[r]);
    } else {
        int idx = (b - 784) * 256 + tid;        // 0..18431 = 36*8*64
        int lane = idx & 63;
        int f = (idx >> 6) & 7;
        int step = idx >> 9;                    // tap*4 + kg
        int tap = step >> 2;
        int c0 = (step & 3) << 5;
        int cout = f * 16 + (lane & 15);
        int cb = c0 + (lane >> 4) * 8;
        short8 v;
#pragma unroll
        for (int j = 0; j < 8; ++j)
            v[j] = (short)f2b(w[((size_t)cout * CIN + cb + j) * 9 + tap]);
        *(short8*)(wr + (size_t)idx * 8) = v;
    }
}

// V: 0=full  1=no-gather(patterned reads)  2=no-interp  3=no-MFMA  4=skeleton
template<int V, int R>
__global__ __launch_bounds__(1024, 4) void deform_main(
    const float* __restrict__ offset, const float* __restrict__ x2,
    const float* __restrict__ bias, const unsigned short* __restrict__ xt,
    const unsigned short* __restrict__ wr, float* __restrict__ out)
{
    extern __shared__ char smem[];
    int*    pmc = (int*)(smem + PMC_OFF);
    float4* pmw = (float4*)(smem + PMW_OFF);
    char*   blds = smem + BLDS_OFF;

    int tid = threadIdx.x;
    int orig = blockIdx.x;                     // 448 = 8 * 56
    int n  = orig & 7;
    int ho = orig >> 3;

    int lane = tid & 63;
    int w16 = tid >> 6;
    int kg = w16 & 3;
    int mt = w16 >> 2;
    int llo = lane & 15, lhi = lane >> 4;
    int cbase = kg * 4 + lhi;

    const char* xim = (const char*)(xt + (size_t)n * HW * CIN);

    // ---- stage 8x56x128ch tile, swizzled (slot = chunk ^ (p&15)) ----
#pragma unroll
    for (int s = 0; s < 7; ++s) {
        int d = (s * 16 + w16) * 1024 + lane * 16;
        int p = d >> 8;
        int tr = p / 56;
        int tx = p - tr * 56;
        int gy = min(max(ho - 3 + tr, 0), 55);
        int c  = ((d >> 4) & 15) ^ (p & 15);
        gload16(xim + (((gy * 56 + tx) << 8) + (c << 4)), smem + d);
    }

    // ---- bilinear params: 576 = 9 taps x 64 px ----
    if (tid < 576) {
        int tap = tid >> 6;
        int px  = tid & 63;
        int wo  = min(px, 55);
        const float* offp = offset + ((size_t)n * 18 + tap * 2) * HW + ho * 56 + wo;
        float offy = offp[0];
        float offx = offp[HW];
        int ki = tap / 3;
        int kj = tap - ki * 3;
        float py = (float)(ho - 1 + ki) + offy;
        float pxf = (float)(wo - 1 + kj) + offx;
        float y0f = floorf(py), x0f = floorf(pxf);
        float wy = py - y0f, wx = pxf - x0f;
        int y0 = (int)y0f, x0 = (int)x0f;
        int y1 = y0 + 1, x1 = x0 + 1;
        bool vy0 = (y0 >= 0) && (y0 < H_IN);
        bool vy1 = (y1 >= 0) && (y1 < H_IN);
        bool vx0 = (x0 >= 0) && (x0 < W_IN);
        bool vx1 = (x1 >= 0) && (x1 < W_IN);
        int cy0 = min(max(y0, 0), 55), cy1 = min(max(y1, 0), 55);
        int cx0 = min(max(x0, 0), 55), cx1 = min(max(x1, 0), 55);
        int f0 = (y0 < ho - 3 || y0 > ho + 4) ? 1 : 0;
        int f1 = (y1 < ho - 3 || y1 > ho + 4) ? 1 : 0;
        pmc[tid] = cy0 | (cy1 << 6) | (cx0 << 12) | (cx1 << 18) | (f0 << 24) | (f1 << 25);
        float4 wv;
        wv.x = (vy0 && vx0) ? (1.f - wy) * (1.f - wx) : 0.f;
        wv.y = (vy0 && vx1) ? (1.f - wy) * wx : 0.f;
        wv.z = (vy1 && vx0) ? wy * (1.f - wx) : 0.f;
        wv.w = (vy1 && vx1) ? wy * wx : 0.f;
        pmw[tid] = wv;
    }

    // ---- T14 B prologue ----
    const char* wrt = (const char*)wr;
    short8 br0 = *(const short8*)(wrt + tid * 32);
    short8 br1 = *(const short8*)(wrt + tid * 32 + 16);

    __syncthreads();

    f32x4 acc[8] = {};

    for (int rep = 0; rep < R; ++rep) {
        for (int tap = 0; tap < 9; ++tap) {
            *(short8*)(blds + tid * 32)      = br0;
            *(short8*)(blds + tid * 32 + 16) = br1;
            __syncthreads();
            if (tap < 8) {
                br0 = *(const short8*)(wrt + (size_t)(tap + 1) * 32768 + tid * 32);
                br1 = *(const short8*)(wrt + (size_t)(tap + 1) * 32768 + tid * 32 + 16);
            }

            if constexpr (V != 4) {
                short8 g0, g1, g2, g3;
                if constexpr (V == 1) {
                    // patterned, conflict-benign LDS reads (same count, no indirection)
                    int p0 = mt * 16 + llo;
                    int p1 = p0 + 64, p2 = p0 + 128, p3 = p0 + 192;
                    g0 = *(const short8*)(smem + (p0 << 8) + ((cbase ^ (p0 & 15)) << 4));
                    g1 = *(const short8*)(smem + (p1 << 8) + ((cbase ^ (p1 & 15)) << 4));
                    g2 = *(const short8*)(smem + (p2 << 8) + ((cbase ^ (p2 & 15)) << 4));
                    g3 = *(const short8*)(smem + (p3 << 8) + ((cbase ^ (p3 & 15)) << 4));
                } else {
                    int cw = pmc[tap * 64 + mt * 16 + llo];
                    int cy0 = cw & 63, cy1 = (cw >> 6) & 63;
                    int cx0 = (cw >> 12) & 63, cx1 = (cw >> 18) & 63;
                    int f0 = (cw >> 24) & 1, f1 = (cw >> 25) & 1;
                    float4 Wf = pmw[tap * 64 + mt * 16 + llo];
                    int tr, p, slot;
                    tr = min(max(cy0 + 3 - ho, 0), TROWS - 1);
                    p = tr * 56 + cx0; slot = cbase ^ (p & 15);
                    g0 = *(const short8*)(smem + (p << 8) + (slot << 4));
                    p = tr * 56 + cx1; slot = cbase ^ (p & 15);
                    g1 = *(const short8*)(smem + (p << 8) + (slot << 4));
                    tr = min(max(cy1 + 3 - ho, 0), TROWS - 1);
                    p = tr * 56 + cx0; slot = cbase ^ (p & 15);
                    g2 = *(const short8*)(smem + (p << 8) + (slot << 4));
                    p = tr * 56 + cx1; slot = cbase ^ (p & 15);
                    g3 = *(const short8*)(smem + (p << 8) + (slot << 4));
                    bool b0 = f0 && (Wf.x != 0.f), b1 = f0 && (Wf.y != 0.f);
                    bool b2 = f1 && (Wf.z != 0.f), b3 = f1 && (Wf.w != 0.f);
                    if (__any(b0 | b1 | b2 | b3)) {
                        if (b0) g0 = *(const short8*)(xim + ((size_t)(cy0 * 56 + cx0) << 8) + (cbase << 4));
                        if (b1) g1 = *(const short8*)(xim + ((size_t)(cy0 * 56 + cx1) << 8) + (cbase << 4));
                        if (b2) g2 = *(const short8*)(xim + ((size_t)(cy1 * 56 + cx0) << 8) + (cbase << 4));
                        if (b3) g3 = *(const short8*)(xim + ((size_t)(cy1 * 56 + cx1) << 8) + (cbase << 4));
                    }
                }

                short8 a;
                if constexpr (V == 2) {
                    keep8(g1); keep8(g2); keep8(g3);
                    a = g0;
                } else {
                    float4 Wf = pmw[tap * 64 + mt * 16 + llo];
#pragma unroll
                    for (int j = 0; j < 8; ++j) {
                        float r = Wf.x * b2f((unsigned short)g0[j])
                                + Wf.y * b2f((unsigned short)g1[j])
                                + Wf.z * b2f((unsigned short)g2[j])
                                + Wf.w * b2f((unsigned short)g3[j]);
                        a[j] = (short)f2b(r);
                    }
                }

                if constexpr (V == 3) {
                    keep8(a);
                } else {
#pragma unroll
                    for (int f = 0; f < 8; ++f) {
                        short8 bf = *(const short8*)(blds + (kg * 8 + f) * 1024 + lane * 16);
                        acc[f] = __builtin_amdgcn_mfma_f32_16x16x32_bf16(a, bf, acc[f], 0, 0, 0);
                    }
                }
            }
            __syncthreads();
        }
    }

    if constexpr (V == 0 && R == 1) {
        // ---- split-K reduction + real epilogue ----
        float* red = (float*)smem;
        if (kg > 0) {
#pragma unroll
            for (int f = 0; f < 8; ++f)
                *(f32x4*)&red[((((kg - 1) * 4 + mt) * 8 + f) * 64 + lane) * 4] = acc[f];
        }
        __syncthreads();
        if (kg == 0) {
#pragma unroll
            for (int g = 0; g < 3; ++g)
#pragma unroll
                for (int f = 0; f < 8; ++f)
                    acc[f] += *(const f32x4*)&red[(((g * 4 + mt) * 8 + f) * 64 + lane) * 4];
            int wo4 = mt * 16 + lhi * 4;
            if (wo4 < 56) {
#pragma unroll
                for (int f = 0; f < 8; ++f) {
                    int cout = f * 16 + llo;
                    float bb = bias[cout];
                    size_t off = ((size_t)(n * COUT + cout)) * HW + ho * 56 + wo4;
                    f32x4 xv = *(const f32x4*)(x2 + off);
                    f32x4 o;
#pragma unroll
                    for (int r = 0; r < 4; ++r) {
                        float v = acc[f][r] + bb + xv[r];
                        o[r] = v > 0.f ? v : 0.f;
                    }
                    *(f32x4*)(out + off) = o;
                }
            }
        }
    } else {
        // ablation: dump junk accumulator to scrap (deterministic, keeps all live)
        *(f32x4*)(out + ((size_t)blockIdx.x * 1024 + tid) * 4) = acc[0];
    }
}

extern "C" void kernel_launch(void* const* d_in, const int* in_sizes, int n_in,
                              void* d_out, int out_size, void* d_ws, size_t ws_size,
                              hipStream_t stream) {
    const float* x      = (const float*)d_in[0];
    const float* offset = (const float*)d_in[1];
    const float* weight = (const float*)d_in[2];
    const float* bias   = (const float*)d_in[3];
    const float* x2     = (const float*)d_in[4];
    float* out = (float*)d_out;

    unsigned short* xt = (unsigned short*)d_ws;
    unsigned short* wr = (unsigned short*)((char*)d_ws + 6422528ULL);
    float* scrap = (float*)((char*)d_ws + SCRAP_OFF);

    hipFuncSetAttribute((const void*)(deform_main<0,1>), hipFuncAttributeMaxDynamicSharedMemorySize, SMEM_TOTAL);
    hipFuncSetAttribute((const void*)(deform_main<0,2>), hipFuncAttributeMaxDynamicSharedMemorySize, SMEM_TOTAL);
    hipFuncSetAttribute((const void*)(deform_main<1,4>), hipFuncAttributeMaxDynamicSharedMemorySize, SMEM_TOTAL);
    hipFuncSetAttribute((const void*)(deform_main<2,2>), hipFuncAttributeMaxDynamicSharedMemorySize, SMEM_TOTAL);
    hipFuncSetAttribute((const void*)(deform_main<3,2>), hipFuncAttributeMaxDynamicSharedMemorySize, SMEM_TOTAL);
    hipFuncSetAttribute((const void*)(deform_main<4,6>), hipFuncAttributeMaxDynamicSharedMemorySize, SMEM_TOTAL);

    prep_kernel<<<856, 256, 0, stream>>>(x, weight, xt, wr);
    // real output (identical to R5 pipeline)
    deform_main<0,1><<<448, 1024, SMEM_TOTAL, stream>>>(offset, x2, bias, xt, wr, out);
    // ablation suite -> scrap
    deform_main<0,2><<<448, 1024, SMEM_TOTAL, stream>>>(offset, x2, bias, xt, wr, scrap); // A full
    deform_main<1,4><<<448, 1024, SMEM_TOTAL, stream>>>(offset, x2, bias, xt, wr, scrap); // B no-gather
    deform_main<2,2><<<448, 1024, SMEM_TOTAL, stream>>>(offset, x2, bias, xt, wr, scrap); // C no-interp
    deform_main<3,2><<<448, 1024, SMEM_TOTAL, stream>>>(offset, x2, bias, xt, wr, scrap); // D no-MFMA
    deform_main<4,6><<<448, 1024, SMEM_TOTAL, stream>>>(offset, x2, bias, xt, wr, scrap); // E skeleton
}

// Round 9
// 38.023 us; speedup vs baseline: 7.8967x; 7.8967x over previous
//
#include <hip/hip_runtime.h>

#define N_IMG 8
#define CIN   128
#define H_IN  56
#define W_IN  56
#define COUT  128
#define HW    3136
#define TROWS 9                        // tile rows [ro0-3, ro0+5], 2 output rows
#define TILE_B (TROWS * 56 * 256)      // 129024
#define PMC_OFF TILE_B                 // int[1152]   -> 4608
#define PMW_OFF (TILE_B + 4608)        // ushort4[1152] -> 9216
#define SMEM_TOTAL (TILE_B + 4608 + 9216)   // 142848 <= 163840

typedef __attribute__((ext_vector_type(8))) short short8;
typedef __attribute__((ext_vector_type(4))) float f32x4;
typedef _Float16 h8 __attribute__((ext_vector_type(8)));

__device__ __forceinline__ unsigned short hb(float f) {
    _Float16 h = (_Float16)f;
    return __builtin_bit_cast(unsigned short, h);
}
__device__ __forceinline__ h8 splat8(unsigned short b) {
    _Float16 s = __builtin_bit_cast(_Float16, b);
    return (h8){s, s, s, s, s, s, s, s};
}
__device__ __forceinline__ void gload16(const void* g, void* l) {
    __builtin_amdgcn_global_load_lds(
        (const __attribute__((address_space(1))) unsigned int*)g,
        (__attribute__((address_space(3))) unsigned int*)l, 16, 0, 0);
}

// blocks 0..783: x (N,C,H,W) f32 -> xt (N,H,W,C) f16
// blocks 784..855: weight -> wr[(tap*4+kc4)*8+f][lane64][8] f16 (B-fragment-linear)
__global__ __launch_bounds__(256) void prep_kernel(const float* __restrict__ x,
                                                   const float* __restrict__ w,
                                                   unsigned short* __restrict__ xt,
                                                   unsigned short* __restrict__ wr) {
    int b = blockIdx.x;
    int tid = threadIdx.x;
    if (b < 784) {
        int c = tid & 127;
        int half = tid >> 7;
        int n = b / 98;
        int hw0 = (b - n * 98) * 32 + half * 16;
        const float* xp = x + ((size_t)(n * CIN + c)) * HW + hw0;
        unsigned short* op = xt + ((size_t)n * HW + hw0) * CIN + c;
#pragma unroll
        for (int r = 0; r < 16; ++r) op[r * CIN] = hb(xp[r]);
    } else {
        int G = (b - 784) * 256 + tid;          // 0..18431 = 36*8*64
        int lane = G & 63;
        int f = (G >> 6) & 7;
        int kc4 = (G >> 9) & 3;
        int tap = G >> 11;
        int cout = f * 16 + (lane & 15);
        int ch = kc4 * 32 + (lane >> 4) * 8;
        short8 v;
#pragma unroll
        for (int j = 0; j < 8; ++j)
            v[j] = (short)hb(w[((size_t)cout * CIN + ch + j) * 9 + tap]);
        *(short8*)(wr + (size_t)G * 8) = v;
    }
}

__global__ __launch_bounds__(1024, 4) void deform_main(
    const float* __restrict__ offset, const float* __restrict__ x2,
    const float* __restrict__ bias, const unsigned short* __restrict__ xt,
    const unsigned short* __restrict__ wr, float* __restrict__ out)
{
    extern __shared__ char smem[];
    int*     pmc = (int*)(smem + PMC_OFF);
    ushort4* pmw = (ushort4*)(smem + PMW_OFF);

    int tid = threadIdx.x;
    int orig = blockIdx.x;                 // 224 = 8 images * 28 row-pairs
    int n   = orig & 7;                    // one image per XCD
    int ro0 = (orig >> 3) * 2;             // first of 2 output rows

    const char* xim = (const char*)(xt + (size_t)n * HW * CIN);

    // ---- stage 9x56x128ch f16 tile, swizzled (slot = chunk ^ (p&15)) ----
#pragma unroll
    for (int s = 0; s < 8; ++s) {
        int d = s * 16384 + tid * 16;
        if (d < TILE_B) {
            int p = d >> 8;                // tile-linear pixel 0..503
            int tr = p / 56;
            int tx = p - tr * 56;
            int gy = min(max(ro0 - 3 + tr, 0), 55);
            int c  = ((d >> 4) & 15) ^ (p & 15);
            gload16(xim + (((gy * 56 + tx) << 8) + (c << 4)), smem + d);
        }
    }

    // ---- bilinear params: 1152 = 2 rows x 9 taps x 64 px ----
    for (int e = tid; e < 1152; e += 1024) {
        int r = (e >= 576) ? 1 : 0;
        int e2 = e - r * 576;
        int tap = e2 >> 6;
        int px  = e2 & 63;
        int wo  = min(px, 55);
        int hor = ro0 + r;
        const float* offp = offset + ((size_t)n * 18 + tap * 2) * HW + hor * 56 + wo;
        float offy = offp[0];
        float offx = offp[HW];
        int ki = tap / 3;
        int kj = tap - ki * 3;
        float py  = (float)(hor - 1 + ki) + offy;
        float pxf = (float)(wo - 1 + kj) + offx;
        float y0f = floorf(py), x0f = floorf(pxf);
        float wy = py - y0f, wx = pxf - x0f;
        int y0 = (int)y0f, x0 = (int)x0f;
        int y1 = y0 + 1, x1 = x0 + 1;
        bool vy0 = (y0 >= 0) && (y0 < H_IN);
        bool vy1 = (y1 >= 0) && (y1 < H_IN);
        bool vx0 = (x0 >= 0) && (x0 < W_IN);
        bool vx1 = (x1 >= 0) && (x1 < W_IN);
        int cy0 = min(max(y0, 0), 55), cy1 = min(max(y1, 0), 55);
        int cx0 = min(max(x0, 0), 55), cx1 = min(max(x1, 0), 55);
        int f0 = (y0 < ro0 - 3 || y0 > ro0 + 5) ? 1 : 0;   // outside 9-row tile
        int f1 = (y1 < ro0 - 3 || y1 > ro0 + 5) ? 1 : 0;
        pmc[e] = cy0 | (cy1 << 6) | (cx0 << 12) | (cx1 << 18) | (f0 << 24) | (f1 << 25);
        ushort4 wp;
        wp.x = hb((vy0 && vx0) ? (1.f - wy) * (1.f - wx) : 0.f);
        wp.y = hb((vy0 && vx1) ? (1.f - wy) * wx : 0.f);
        wp.z = hb((vy1 && vx0) ? wy * (1.f - wx) : 0.f);
        wp.w = hb((vy1 && vx1) ? wy * wx : 0.f);
        pmw[e] = wp;
    }
    __syncthreads();   // tile + params visible; only barrier before epilogue

    int lane = tid & 63;
    int w16 = tid >> 6;            // 16 waves = 2 kg x 8 mt
    int kg = w16 & 1;              // 64-ch half
    int mt = w16 >> 1;             // 16-px slot group (slots 0..127 over 2 rows)
    int llo = lane & 15, lhi = lane >> 4;
    int slot = mt * 16 + llo;
    int row = slot >> 6;
    int px  = slot & 63;
    int ebase = row * 576 + px;
    const char* wrb = (const char*)wr;

    f32x4 acc[8] = {};

    for (int tap = 0; tap < 9; ++tap) {
        int cw = pmc[ebase + tap * 64];
        ushort4 wp = pmw[ebase + tap * 64];
        int cy0 = cw & 63, cy1 = (cw >> 6) & 63;
        int cx0 = (cw >> 12) & 63, cx1 = (cw >> 18) & 63;
        int f0 = (cw >> 24) & 1, f1 = (cw >> 25) & 1;
        int tr0 = min(max(cy0 + 3 - ro0, 0), TROWS - 1);
        int tr1 = min(max(cy1 + 3 - ro0, 0), TROWS - 1);
        int p00 = tr0 * 56 + cx0, p01 = tr0 * 56 + cx1;
        int p10 = tr1 * 56 + cx0, p11 = tr1 * 56 + cx1;
        bool any_fb = __any((f0 & ((wp.x != 0) | (wp.y != 0))) |
                            (f1 & ((wp.z != 0) | (wp.w != 0))));

#pragma unroll
        for (int kc = 0; kc < 2; ++kc) {
            int cbase = kg * 8 + kc * 4 + lhi;   // 16B chunk within 256B px block
            h8 g0 = *(const h8*)(smem + (p00 << 8) + ((cbase ^ (p00 & 15)) << 4));
            h8 g1 = *(const h8*)(smem + (p01 << 8) + ((cbase ^ (p01 & 15)) << 4));
            h8 g2 = *(const h8*)(smem + (p10 << 8) + ((cbase ^ (p10 & 15)) << 4));
            h8 g3 = *(const h8*)(smem + (p11 << 8) + ((cbase ^ (p11 & 15)) << 4));
            if (any_fb) {   // rare (~2%): corner outside tile rows, weight != 0
                if (f0 && (wp.x != 0)) g0 = *(const h8*)(xim + ((size_t)(cy0 * 56 + cx0) << 8) + (cbase << 4));
                if (f0 && (wp.y != 0)) g1 = *(const h8*)(xim + ((size_t)(cy0 * 56 + cx1) << 8) + (cbase << 4));
                if (f1 && (wp.z != 0)) g2 = *(const h8*)(xim + ((size_t)(cy1 * 56 + cx0) << 8) + (cbase << 4));
                if (f1 && (wp.w != 0)) g3 = *(const h8*)(xim + ((size_t)(cy1 * 56 + cx1) << 8) + (cbase << 4));
            }
            h8 a = g0 * splat8(wp.x) + g1 * splat8(wp.y)
                 + g2 * splat8(wp.z) + g3 * splat8(wp.w);

            const char* bb = wrb + (size_t)((tap * 4 + kg * 2 + kc) * 8) * 1024 + lane * 16;
#pragma unroll
            for (int f = 0; f < 8; ++f) {
                h8 bf = *(const h8*)(bb + f * 1024);
                acc[f] = __builtin_amdgcn_mfma_f32_16x16x32_f16(a, bf, acc[f], 0, 0, 0);
            }
        }
    }

    // ---- split-K (kg=1 -> kg=0) via LDS, then epilogue ----
    __syncthreads();                       // loop reads of tile done WG-wide
    if (kg == 1) {
#pragma unroll
        for (int f = 0; f < 8; ++f)
            *(f32x4*)(smem + (((mt * 8 + f) * 64 + lane) << 4)) = acc[f];
    }
    __syncthreads();
    if (kg == 0) {
#pragma unroll
        for (int f = 0; f < 8; ++f)
            acc[f] += *(const f32x4*)(smem + (((mt * 8 + f) * 64 + lane) << 4));

        int slotq = mt * 16 + lhi * 4;     // 4 consecutive px slots
        int srow = slotq >> 6;
        int wo4 = slotq & 63;
        if (wo4 < 56) {
#pragma unroll
            for (int f = 0; f < 8; ++f) {
                int cout = f * 16 + llo;
                float bb = bias[cout];
                size_t off = ((size_t)(n * COUT + cout)) * HW + (ro0 + srow) * 56 + wo4;
                f32x4 xv = *(const f32x4*)(x2 + off);
                f32x4 o;
#pragma unroll
                for (int r = 0; r < 4; ++r) {
                    float v = acc[f][r] + bb + xv[r];
                    o[r] = v > 0.f ? v : 0.f;
                }
                *(f32x4*)(out + off) = o;
            }
        }
    }
}

extern "C" void kernel_launch(void* const* d_in, const int* in_sizes, int n_in,
                              void* d_out, int out_size, void* d_ws, size_t ws_size,
                              hipStream_t stream) {
    const float* x      = (const float*)d_in[0];
    const float* offset = (const float*)d_in[1];
    const float* weight = (const float*)d_in[2];
    const float* bias   = (const float*)d_in[3];
    const float* x2     = (const float*)d_in[4];
    float* out = (float*)d_out;

    unsigned short* xt = (unsigned short*)d_ws;                     // 6,422,528 B
    unsigned short* wr = (unsigned short*)((char*)d_ws + 6422528ULL); // 294,912 B

    hipFuncSetAttribute((const void*)deform_main,
                        hipFuncAttributeMaxDynamicSharedMemorySize, SMEM_TOTAL);
    prep_kernel<<<856, 256, 0, stream>>>(x, weight, xt, wr);
    deform_main<<<224, 1024, SMEM_TOTAL, stream>>>(offset, x2, bias, xt, wr, out);
}